// Round 1
// baseline (691.539 us; speedup 1.0000x reference)
//
#include <hip/hip_runtime.h>

// Problem: B=4096, F=128, E=128, NS=10
//   neigh_mean[b] = mean_{k<10} features[neigh_idx[b,k]]       [128]
//   combined[b]   = concat(features[nodes[b]], neigh_mean[b])  [256]
//   out[b]        = relu(combined[b] @ weight[b])              [128]
// weight[b] is [256,128] row-major; 512 MiB total, streamed once -> HBM-bound.

constexpr int FEAT  = 128;
constexpr int EMBED = 128;
constexpr int NSAMP = 10;
constexpr int TWOF  = 2 * FEAT;

__global__ __launch_bounds__(256) void encoder_kernel(
    const float* __restrict__ features,
    const float* __restrict__ weight,
    const int*   __restrict__ nodes,
    const int*   __restrict__ neigh_idx,
    float*       __restrict__ out)
{
    const int b = blockIdx.x;
    const int t = threadIdx.x;

    __shared__ float c[TWOF];              // combined input vector
    __shared__ float partial[8 * 32 * 4];  // [seg][quad][4] = 4 KB

    // Build combined vector. Waves 0-1: self feats; waves 2-3: neighbor mean.
    if (t < FEAT) {
        const int node = nodes[b];
        c[t] = features[(size_t)node * FEAT + t];
    } else {
        const int f = t - FEAT;
        float s = 0.f;
#pragma unroll
        for (int k = 0; k < NSAMP; ++k) {
            const int n = neigh_idx[b * NSAMP + k];
            s += features[(size_t)n * FEAT + f];
        }
        c[FEAT + f] = s * (1.0f / NSAMP);
    }
    __syncthreads();

    // Stream the 128KB weight tile: thread t owns output quad (t&31),
    // i-segment (t>>5). Coalesced float4 loads, 16B/lane.
    const int quad = t & 31;
    const int seg  = t >> 5;
    const float4* __restrict__ wtile =
        (const float4*)(weight + (size_t)b * TWOF * EMBED);

    float4 acc = make_float4(0.f, 0.f, 0.f, 0.f);
#pragma unroll 8
    for (int ii = 0; ii < 32; ++ii) {
        const int i = seg * 32 + ii;
        const float4 w = wtile[(size_t)i * 32 + quad];
        const float ci = c[i];
        acc.x = fmaf(ci, w.x, acc.x);
        acc.y = fmaf(ci, w.y, acc.y);
        acc.z = fmaf(ci, w.z, acc.z);
        acc.w = fmaf(ci, w.w, acc.w);
    }

    float* p = &partial[(seg * 32 + quad) * 4];
    p[0] = acc.x; p[1] = acc.y; p[2] = acc.z; p[3] = acc.w;
    __syncthreads();

    // Reduce 8 segments per output element; partial[sgi*128 + t] is the
    // partial for output t from segment sgi (2-way LDS aliasing = free).
    if (t < EMBED) {
        float s = 0.f;
#pragma unroll
        for (int sgi = 0; sgi < 8; ++sgi)
            s += partial[sgi * 128 + t];
        out[(size_t)b * EMBED + t] = fmaxf(s, 0.f);
    }
}

extern "C" void kernel_launch(void* const* d_in, const int* in_sizes, int n_in,
                              void* d_out, int out_size, void* d_ws, size_t ws_size,
                              hipStream_t stream) {
    const float* features = (const float*)d_in[0];   // [100000,128] f32
    const float* weight   = (const float*)d_in[1];   // [4096,256,128] f32
    const int*   nodes    = (const int*)d_in[2];     // [4096] i32
    const int*   neigh    = (const int*)d_in[3];     // [4096,10] i32
    float*       outp     = (float*)d_out;           // [4096,128] f32

    const int batch = in_sizes[2];  // 4096
    encoder_kernel<<<batch, 256, 0, stream>>>(features, weight, nodes, neigh, outp);
}

// Round 3
// 679.244 us; speedup vs baseline: 1.0181x; 1.0181x over previous
//
#include <hip/hip_runtime.h>

// B=4096, F=128, E=128, NS=10
//   out[b] = relu(concat(features[nodes[b]], mean_k features[neigh_idx[b,k]]) @ weight[b])
// weight: [4096,256,128] f32 = 512 MiB, read exactly once -> HBM-bound, floor ~85us.
// Design: 1 block/b. Weight streamed with NONTEMPORAL loads (read-once; keeps the
// 51 MB features table L3-resident for the gathers). Gather latency hidden under
// the first prefetched weight chunk. 2-stage software pipeline, 8 dwordx4 in flight.

constexpr int FEAT  = 128;
constexpr int EMBED = 128;
constexpr int NSAMP = 10;
constexpr int TWOF  = 2 * FEAT;

// Native clang vector type: __builtin_nontemporal_load requires it
// (HIP's float4 is a struct and is rejected).
typedef float v4f __attribute__((ext_vector_type(4)));

__global__ __launch_bounds__(256) void encoder_kernel(
    const float* __restrict__ features,
    const float* __restrict__ weight,
    const int*   __restrict__ nodes,
    const int*   __restrict__ neigh_idx,
    float*       __restrict__ out)
{
    const int b = blockIdx.x;
    const int t = threadIdx.x;

    __shared__ float c[TWOF];            // combined input vector
    __shared__ float partial[8 * 128];   // [seg][embed] 4 KB

    // ---- Gather into registers (no LDS yet, no sync yet) ----
    float gval;
    if (t < FEAT) {
        const int node = nodes[b];
        gval = features[(size_t)node * FEAT + t];
    } else {
        const int f = t - FEAT;
        float s = 0.f;
#pragma unroll
        for (int k = 0; k < NSAMP; ++k) {
            const int n = neigh_idx[b * NSAMP + k];
            s += features[(size_t)n * FEAT + f];
        }
        gval = s * (1.0f / NSAMP);
    }

    // Thread t owns output quad (t&31), row-segment (t>>5): rows seg*32..seg*32+31.
    const int quad = t & 31;
    const int seg  = t >> 5;
    const v4f* __restrict__ wtile =
        (const v4f*)(weight + (size_t)b * TWOF * EMBED)
        + (size_t)seg * 32 * 32 + quad;

    // ---- Prefetch chunk 0 (8 rows) BEFORE the barrier: hides gather latency ----
    v4f w[8];
#pragma unroll
    for (int j = 0; j < 8; ++j)
        w[j] = __builtin_nontemporal_load(wtile + j * 32);

    c[t] = gval;
    __syncthreads();

    // ---- Main stream: 4 chunks x 8 rows, 2-stage pipeline ----
    float accx = 0.f, accy = 0.f, accz = 0.f, accw = 0.f;
#pragma unroll
    for (int chunk = 0; chunk < 4; ++chunk) {
        v4f wn[8];
        if (chunk < 3) {
#pragma unroll
            for (int j = 0; j < 8; ++j)
                wn[j] = __builtin_nontemporal_load(wtile + ((chunk + 1) * 8 + j) * 32);
        }
#pragma unroll
        for (int j = 0; j < 8; ++j) {
            const float ci = c[seg * 32 + chunk * 8 + j];
            accx = fmaf(ci, w[j].x, accx);
            accy = fmaf(ci, w[j].y, accy);
            accz = fmaf(ci, w[j].z, accz);
            accw = fmaf(ci, w[j].w, accw);
        }
        if (chunk < 3) {
#pragma unroll
            for (int j = 0; j < 8; ++j) w[j] = wn[j];
        }
    }

    // partial[seg][quad*4 + 0..3]
    float* p = &partial[seg * 128 + quad * 4];
    p[0] = accx; p[1] = accy; p[2] = accz; p[3] = accw;
    __syncthreads();

    // ---- Reduce 8 segments per output element, ReLU, coalesced store ----
    if (t < EMBED) {
        float s = 0.f;
#pragma unroll
        for (int sgi = 0; sgi < 8; ++sgi)
            s += partial[sgi * 128 + t];
        out[(size_t)b * EMBED + t] = fmaxf(s, 0.f);
    }
}

extern "C" void kernel_launch(void* const* d_in, const int* in_sizes, int n_in,
                              void* d_out, int out_size, void* d_ws, size_t ws_size,
                              hipStream_t stream) {
    const float* features = (const float*)d_in[0];   // [100000,128] f32
    const float* weight   = (const float*)d_in[1];   // [4096,256,128] f32
    const int*   nodes    = (const int*)d_in[2];     // [4096] i32
    const int*   neigh    = (const int*)d_in[3];     // [4096,10] i32
    float*       outp     = (float*)d_out;           // [4096,128] f32

    const int batch = in_sizes[2];  // 4096
    encoder_kernel<<<batch, 256, 0, stream>>>(features, weight, nodes, neigh, outp);
}